// Round 10
// baseline (575.535 us; speedup 1.0000x reference)
//
#include <hip/hip_runtime.h>
#include <cstdint>
#include <cstddef>

#define NB 8
#define NPTS 8192
#define S_TOT 512
#define NSAMP 64
#define DFEAT 64
#define INCH 67
#define SLOTS 17
#define CCAP (SLOTS * 256)   // 4352 compacted slots per (b,grp); CCAP*16 = 69632 B
#define TDONE 1060           // 1024 transpose + 36 pack completions
#define BALLW 13568          // per-wave LDS slice for ball path (13312 sBuf + 256 s_idx)
#define SMEMSZ 82048         // > 81920 => 1 block/CU: FPS CUs host nothing else

typedef __attribute__((ext_vector_type(8))) short v8s;
typedef __attribute__((ext_vector_type(4))) short v4s;
typedef __attribute__((ext_vector_type(4))) float v4f;

// exact (numpy-matching) squared distance: (a-b) per component, square, sum as (x+y)+z
__device__ __forceinline__ float d2_exact(float ax, float ay, float az,
                                          float bx, float by, float bz) {
    float dx = __fsub_rn(ax, bx);
    float dy = __fsub_rn(ay, by);
    float dz = __fsub_rn(az, bz);
    return __fadd_rn(__fadd_rn(__fmul_rn(dx, dx), __fmul_rn(dy, dy)), __fmul_rn(dz, dz));
}

// fp32 -> bf16 round-to-nearest-even
__device__ __forceinline__ unsigned short f2b(float f) {
    unsigned u = __float_as_uint(f);
    return (unsigned short)((u + 0x7fffu + ((u >> 16) & 1u)) >> 16);
}

// write-through (coherent) store helpers: land at LLC, never dirty in L2.
__device__ __forceinline__ void st_wt_f32(float* p, float v) {
    __hip_atomic_store(p, v, __ATOMIC_RELAXED, __HIP_MEMORY_SCOPE_AGENT);
}
__device__ __forceinline__ void st_wt_u32(unsigned* p, unsigned v) {
    __hip_atomic_store(p, v, __ATOMIC_RELAXED, __HIP_MEMORY_SCOPE_AGENT);
}
__device__ __forceinline__ void st_wt_u64(unsigned long long* p, unsigned long long v) {
    __hip_atomic_store(p, v, __ATOMIC_RELAXED, __HIP_MEMORY_SCOPE_AGENT);
}

template <int CTRL>
__device__ __forceinline__ unsigned long long dpp_max_u64(unsigned long long k) {
    int lo = (int)(unsigned)(k & 0xffffffffull);
    int hi = (int)(unsigned)(k >> 32);
    int slo = __builtin_amdgcn_update_dpp(lo, lo, CTRL, 0xf, 0xf, false);
    int shi = __builtin_amdgcn_update_dpp(hi, hi, CTRL, 0xf, 0xf, false);
    unsigned long long o = ((unsigned long long)(unsigned)shi << 32) | (unsigned)slo;
    return (o > k) ? o : k;
}

// ---------------------------------------------------------------------------
// Ball query + MFMA MLP + max for ONE query point, one wave (R10-verified
// body, absmax 0.015625). LDS comes in as a per-wave slice.
// ---------------------------------------------------------------------------
__device__ __forceinline__ void ball_one(
    const float* __restrict__ xyz,
    const unsigned short* __restrict__ ptsTh,
    const unsigned short* __restrict__ wp,
    const float* __restrict__ b0, const float* __restrict__ b1,
    const float* __restrict__ b2,
    const float* __restrict__ out0, float* __restrict__ out1,
    int b, int sg, int lane, short* sBuf, int* s_idx)
{
    const float R2 = (float)(0.4 * 0.4);   // 0x3E23D70A — NOT 0.4f*0.4f
    int col = lane & 15, quad = lane >> 4, kq = quad * 8;

    const float* xb = xyz + (size_t)b * 3 * NPTS;
    float qx = out0[(size_t)b * 3 * S_TOT + sg];
    float qy = out0[(size_t)b * 3 * S_TOT + S_TOT + sg];
    float qz = out0[(size_t)b * 3 * S_TOT + 2 * S_TOT + sg];

    unsigned long long* s_mask = (unsigned long long*)sBuf;  // phase A: 1 KB

    // ---- phase 1: independent ballots ----
#pragma unroll 8
    for (int j = 0; j < 128; j++) {
        int n = j * 64 + lane;
        float d2 = d2_exact(qx, qy, qz, xb[n], xb[NPTS + n], xb[2 * NPTS + n]);
        unsigned long long m = __ballot(d2 < R2);
        if (lane == 0) s_mask[j] = m;
    }

    // ---- phase 2: prefix over 128 chunk popcounts ----
    unsigned long long m0 = s_mask[lane];
    unsigned long long m1 = s_mask[64 + lane];
    int c0 = (int)__popcll(m0), c1 = (int)__popcll(m1);
    int i0 = c0;
#pragma unroll
    for (int off = 1; off <= 32; off <<= 1) {
        int t = __shfl_up(i0, off);
        if (lane >= off) i0 += t;
    }
    int T0 = __shfl(i0, 63);
    int i1 = c1;
#pragma unroll
    for (int off = 1; off <= 32; off <<= 1) {
        int t = __shfl_up(i1, off);
        if (lane >= off) i1 += t;
    }
    int total = T0 + __shfl(i1, 63);
    int p0 = i0 - c0;
    int p1 = T0 + i1 - c1;

    // ---- phase 3: bit expansion into s_idx (global chunk/bit order) ----
    {
        int base = p0, org = lane * 64;
        while (m0 && base < NSAMP) {
            int bp = __ffsll((long long)m0) - 1;
            s_idx[base++] = org + bp;
            m0 &= m0 - 1;
        }
        base = p1; org = (64 + lane) * 64;
        while (m1 && base < NSAMP) {
            int bp = __ffsll((long long)m1) - 1;
            s_idx[base++] = org + bp;
            m1 &= m1 - 1;
        }
    }
    int cnt = (total > NSAMP) ? NSAMP : total;

    int nb = (lane < cnt) ? s_idx[lane] : -1;
    float nx_ = 0.f, ny_ = 0.f, nz_ = 0.f;
    if (nb >= 0) { nx_ = xb[nb]; ny_ = xb[NPTS + nb]; nz_ = xb[2 * NPTS + nb]; }
    float fx = nx_ - qx, fy = ny_ - qy, fz = nz_ - qz;   // pad rows: -new_xyz
    int row = (nb < 0) ? (NPTS - 1) : nb;                // torch -1 wraps to last

    // ---- stage X1 row (stride 104; masks dead, safe to overwrite) ----
    {
        const unsigned short* ph = ptsTh + ((size_t)b * NPTS + row) * DFEAT;
        short* xr = &sBuf[lane * 104];
#pragma unroll
        for (int i = 0; i < 8; i++)
            *(v8s*)(xr + i * 8) = *(const v8s*)(ph + i * 8);
#pragma unroll
        for (int i = 0; i < 5; i++)
            *(v8s*)(xr + 64 + i * 8) = (v8s)0;
        v4s xyzp;
        xyzp[0] = (short)f2b(fx); xyzp[1] = (short)f2b(fy);
        xyzp[2] = (short)f2b(fz); xyzp[3] = 0;
        *(v4s*)(xr + 64) = xyzp;
    }

    const v8s* wpv = (const v8s*)wp;

    // ---- layer 1: [64x96] x [96x64], 3 K-steps ----
    v4f acc[4][4];
#pragma unroll
    for (int nt = 0; nt < 4; nt++) {
        float bb = b0[nt * 16 + col];
#pragma unroll
        for (int mt = 0; mt < 4; mt++) acc[mt][nt] = (v4f){bb, bb, bb, bb};
    }
#pragma unroll
    for (int kt = 0; kt < 3; kt++) {
        v8s bf[4];
#pragma unroll
        for (int nt = 0; nt < 4; nt++) bf[nt] = wpv[(kt * 4 + nt) * 64 + lane];
#pragma unroll
        for (int mt = 0; mt < 4; mt++) {
            v8s a = *(const v8s*)&sBuf[(mt * 16 + col) * 104 + kt * 32 + kq];
#pragma unroll
            for (int nt = 0; nt < 4; nt++)
                acc[mt][nt] = __builtin_amdgcn_mfma_f32_16x16x32_bf16(a, bf[nt], acc[mt][nt], 0, 0, 0);
        }
    }
#pragma unroll
    for (int mt = 0; mt < 4; mt++)
#pragma unroll
        for (int nt = 0; nt < 4; nt++)
#pragma unroll
            for (int r = 0; r < 4; r++)
                sBuf[(mt * 16 + quad * 4 + r) * 72 + nt * 16 + col] =
                    (short)f2b(fmaxf(acc[mt][nt][r], 0.0f));

    // ---- layer 2: [64x64] x [64x64], 2 K-steps ----
#pragma unroll
    for (int nt = 0; nt < 4; nt++) {
        float bb = b1[nt * 16 + col];
#pragma unroll
        for (int mt = 0; mt < 4; mt++) acc[mt][nt] = (v4f){bb, bb, bb, bb};
    }
#pragma unroll
    for (int kt = 0; kt < 2; kt++) {
        v8s bf[4];
#pragma unroll
        for (int nt = 0; nt < 4; nt++) bf[nt] = wpv[(12 + kt * 4 + nt) * 64 + lane];
#pragma unroll
        for (int mt = 0; mt < 4; mt++) {
            v8s a = *(const v8s*)&sBuf[(mt * 16 + col) * 72 + kt * 32 + kq];
#pragma unroll
            for (int nt = 0; nt < 4; nt++)
                acc[mt][nt] = __builtin_amdgcn_mfma_f32_16x16x32_bf16(a, bf[nt], acc[mt][nt], 0, 0, 0);
        }
    }
#pragma unroll
    for (int mt = 0; mt < 4; mt++)
#pragma unroll
        for (int nt = 0; nt < 4; nt++)
#pragma unroll
            for (int r = 0; r < 4; r++)
                sBuf[(mt * 16 + quad * 4 + r) * 72 + nt * 16 + col] =
                    (short)f2b(fmaxf(acc[mt][nt][r], 0.0f));

    // ---- layer 3: [64x64] x [64x128], two passes of 4 N-tiles ----
#pragma unroll
    for (int p = 0; p < 2; p++) {
#pragma unroll
        for (int nt = 0; nt < 4; nt++) {
            float bb = b2[(p * 4 + nt) * 16 + col];
#pragma unroll
            for (int mt = 0; mt < 4; mt++) acc[mt][nt] = (v4f){bb, bb, bb, bb};
        }
#pragma unroll
        for (int kt = 0; kt < 2; kt++) {
            v8s bf[4];
#pragma unroll
            for (int nt = 0; nt < 4; nt++)
                bf[nt] = wpv[(20 + kt * 8 + p * 4 + nt) * 64 + lane];
#pragma unroll
            for (int mt = 0; mt < 4; mt++) {
                v8s a = *(const v8s*)&sBuf[(mt * 16 + col) * 72 + kt * 32 + kq];
#pragma unroll
                for (int nt = 0; nt < 4; nt++)
                    acc[mt][nt] = __builtin_amdgcn_mfma_f32_16x16x32_bf16(a, bf[nt], acc[mt][nt], 0, 0, 0);
            }
        }
#pragma unroll
        for (int nt = 0; nt < 4; nt++) {
            float v = 0.0f;   // relu output >= 0
#pragma unroll
            for (int mt = 0; mt < 4; mt++)
#pragma unroll
                for (int r = 0; r < 4; r++)
                    v = fmaxf(v, acc[mt][nt][r]);
            v = fmaxf(v, __shfl_xor(v, 16));
            v = fmaxf(v, __shfl_xor(v, 32));
            if (lane < 16)
                out1[((size_t)(b * 128 + (p * 4 + nt) * 16 + lane)) * S_TOT + sg] = v;
        }
    }
}

// ---------------------------------------------------------------------------
// FUSED streaming kernel — compaction now IN-FUSED with LDS-staged COALESCED
// write-through output (fixes R20's partial-line write amplification).
//   blocks 0..15     : fps_iter (R21-exact loop); bounded-poll cflag first.
//   blocks 16..31    : compact (R16-verified 256-thr logic) -> LDS scatter ->
//                      coalesced u64 WT copy-out -> cxyz/hdr, publish cflag.
//   blocks 32..1055  : points transpose (+tcount)
//   blocks 1056..1091: weight pack (+tcount)
//   blocks 1092..2115: ball+MLP consumers (production order).
// Control words zeroed by hipMemsetAsync (R16/R20-proven under capture).
// All waits bounded; every timeout path covered by the cleanup kernel.
// ---------------------------------------------------------------------------
__global__ __launch_bounds__(256, 1) void fps_fused(
    const float* __restrict__ attn,
    float4* __restrict__ cxyz,
    int* __restrict__ hdr,
    float* __restrict__ out0, float* __restrict__ out2,
    const float* __restrict__ pts, unsigned short* __restrict__ ptsTh,
    const float* __restrict__ w0, const float* __restrict__ w1,
    const float* __restrict__ w2, unsigned short* __restrict__ wp,
    const float* __restrict__ xyz,
    const float* __restrict__ b0v, const float* __restrict__ b1v,
    const float* __restrict__ b2v,
    float* __restrict__ out1,
    int* __restrict__ prog, int* __restrict__ tcount, int* __restrict__ skip,
    int* __restrict__ fpsdone, int* __restrict__ cflag)
{
    __shared__ __align__(16) char smem[SMEMSZ];   // 82048 B => 1 block/CU
    int blk = blockIdx.x;
    int tid = threadIdx.x;

    if (blk < 16) {
        // ---------------- fps_iter: wait for compact, then R21-exact loop --------
        int b = blk >> 1, grp = blk & 1;
        int K = grp ? 384 : 128;
        int soff = grp ? 128 : 0;
        int lane = tid & 63, wid = tid >> 6;

        // bounded wait for in-fused compact (~10 us; bound ~850 us)
        int cok = 0;
        for (int to = 0; to < 4000; ++to) {
            if (__hip_atomic_load(&cflag[blk], __ATOMIC_RELAXED, __HIP_MEMORY_SCOPE_AGENT)) { cok = 1; break; }
            __builtin_amdgcn_s_sleep(8);
        }
        if (!cok) {
            if (tid == 0)
                __hip_atomic_store(&prog[blk], -1, __ATOMIC_RELAXED, __HIP_MEMORY_SCOPE_AGENT);
            return;                       // fpsdone stays 0 -> cleanup redoes FPS
        }
        __builtin_amdgcn_fence(__ATOMIC_ACQUIRE, "agent");

        int M = hdr[blk * 2];
        int repslot = hdr[blk * 2 + 1];
        if (M > CCAP) {                   // cleanup fallback covers this block
            if (tid == 0)
                __hip_atomic_store(&prog[blk], -1, __ATOMIC_RELAXED, __HIP_MEMORY_SCOPE_AGENT);
            return;
        }
        __builtin_amdgcn_s_setprio(1);

        const float4* cb = cxyz + (size_t)blk * CCAP;
        float4* sc = (float4*)smem;                                   // [CCAP]
        float4* s_obuf = (float4*)(smem + 69632);                     // [384]
        unsigned long long* s_red = (unsigned long long*)(smem + 69632 + 6144); // [2][4]

        float px[SLOTS], py[SLOTS], pz[SLOTS], md[SLOTS];
#pragma unroll
        for (int i = 0; i < SLOTS; i++) {
            int sl = i * 256 + tid;
            bool v = sl < M;
            float4 c = v ? cb[sl] : make_float4(0.f, 0.f, 0.f, 0.f);
            px[i] = c.x; py[i] = c.y; pz[i] = c.z;
            sc[sl] = c;
            md[i] = v ? 1e10f : -1.0f;
        }
        float4 c0 = cb[0];
        float lx = c0.x, ly = c0.y, lz = c0.z;
        float a_last = attn[(size_t)b * NPTS];
        float kept_a = grp ? 0.0f : 1.0f;
        float rep_a  = grp ? 1.0f : 0.0f;
        __syncthreads();                  // staging visible (full drain OK here, once)

        for (int k = 0; k < K; k++) {
            if (tid == 0) s_obuf[k] = make_float4(lx, ly, lz, a_last);
            if (k == K - 1) break;

            float bv = -1.0f; int bslot = 0x7fffffff;
#pragma unroll
            for (int i = 0; i < SLOTS; i++) {
                float d2 = d2_exact(px[i], py[i], pz[i], lx, ly, lz);
                md[i] = fminf(md[i], d2);
                int sl = i * 256 + tid;
                bool w = (md[i] > bv) || ((md[i] == bv) && (sl < bslot));
                bv = w ? md[i] : bv;
                bslot = w ? sl : bslot;
            }
            unsigned long long key = (bv >= 0.0f)
                ? (((unsigned long long)__float_as_uint(bv) << 32) | (unsigned)(~bslot))
                : 0ull;
            key = dpp_max_u64<0x111>(key);
            key = dpp_max_u64<0x112>(key);
            key = dpp_max_u64<0x114>(key);
            key = dpp_max_u64<0x118>(key);
            key = dpp_max_u64<0x142>(key);
            key = dpp_max_u64<0x143>(key);    // lane 63 = wave max
            int buf = k & 1;
            if (lane == 63) s_red[buf * 4 + wid] = key;
            // raw barrier: LDS-only drain; wave 3's publish stores stay in flight.
            asm volatile("s_waitcnt lgkmcnt(0)\n\ts_barrier" ::: "memory");
            __builtin_amdgcn_sched_barrier(0);

            const unsigned long long* rp = &s_red[buf * 4];
            unsigned long long k0 = rp[0], k1 = rp[1], k2 = rp[2], k3 = rp[3];
            unsigned long long m01 = (k0 > k1) ? k0 : k1;
            unsigned long long m23 = (k2 > k3) ? k2 : k3;
            unsigned long long g = (m01 > m23) ? m01 : m23;
            int wslot = (int)(~(unsigned)g);
            float4 wc = sc[wslot];            // ds_read_b128, broadcast
            lx = wc.x; ly = wc.y; lz = wc.z;
            a_last = (wslot == repslot) ? rep_a : kept_a;

            // ---- deferred flush (wave 3): vmcnt(0) covers the batch issued
            // 16 iterations ago (free); publish it; issue new batch, no drain.
            if (((k & 15) == 15) && wid == 3) {
                asm volatile("s_waitcnt vmcnt(0)" ::: "memory");
                if (lane == 0 && k >= 31)
                    __hip_atomic_store(&prog[blk], k - 15, __ATOMIC_RELAXED, __HIP_MEMORY_SCOPE_AGENT);
                if (lane < 16) {
                    int kk = k - 15 + lane;
                    float4 o = s_obuf[kk];
                    int sgO = soff + kk;
                    size_t base = (size_t)b * 3 * S_TOT;
                    st_wt_f32(&out0[base + sgO], o.x);
                    st_wt_f32(&out0[base + S_TOT + sgO], o.y);
                    st_wt_f32(&out0[base + 2 * S_TOT + sgO], o.z);
                    st_wt_f32(&out2[(size_t)b * S_TOT + sgO], o.w);
                }
            }
        }
        __syncthreads();   // full drain (implicit vmcnt 0); last batch done here
        if (wid == 3) {    // publish penultimate batch, store+publish final 16
            if (lane == 0)
                __hip_atomic_store(&prog[blk], K - 16, __ATOMIC_RELAXED, __HIP_MEMORY_SCOPE_AGENT);
            if (lane < 16) {
                int kk = K - 16 + lane;
                float4 o = s_obuf[kk];
                int sgO = soff + kk;
                size_t base = (size_t)b * 3 * S_TOT;
                st_wt_f32(&out0[base + sgO], o.x);
                st_wt_f32(&out0[base + S_TOT + sgO], o.y);
                st_wt_f32(&out0[base + 2 * S_TOT + sgO], o.z);
                st_wt_f32(&out2[(size_t)b * S_TOT + sgO], o.w);
            }
            asm volatile("s_waitcnt vmcnt(0)" ::: "memory");
            if (lane == 0) {
                __hip_atomic_store(&prog[blk], K, __ATOMIC_RELAXED, __HIP_MEMORY_SCOPE_AGENT);
                st_wt_u32((unsigned*)&fpsdone[blk], 1u);   // cleanup gate: FPS done
            }
        }
    } else if (blk < 32) {
        // ---------------- in-fused compact (R16-verified logic) ------------------
        // LDS scatter first, then COALESCED u64 write-through copy-out: full-line
        // transactions, no partial-line amplification (the R20 failure mode).
        int cblk = blk - 16;
        int b = cblk >> 1, grp = cblk & 1;
        int lane = tid & 63, wid = tid >> 6;
        const float* xb = xyz + (size_t)b * 3 * NPTS;
        const float* ab = attn + (size_t)b * NPTS;

        float4* sc = (float4*)smem;                 // [CCAP] staging (69632 B)
        int* s_init = (int*)(smem + 69632);         // [5]: repmin, per-wave totals
        if (tid == 0) s_init[0] = NPTS;
        __syncthreads();

        int n0 = tid * 32;
        unsigned km = 0;
        int cnt = 0;
#pragma unroll
        for (int c = 0; c < 8; c++) {
            float4 a4 = *(const float4*)(ab + n0 + c * 4);
            const float* af = (const float*)&a4;
#pragma unroll
            for (int j = 0; j < 4; j++) {
                bool kp = grp ? (af[j] == 0.0f) : (af[j] != 0.0f);
                if (kp) { km |= 1u << (c * 4 + j); cnt++; }
            }
        }
        if (km != 0xFFFFFFFFu)
            atomicMin(&s_init[0], n0 + __builtin_ctz(~km));   // first not-kept index

        int incl = cnt;
#pragma unroll
        for (int off = 1; off <= 32; off <<= 1) {
            int t = __shfl_up(incl, off);
            if (lane >= off) incl += t;
        }
        if (lane == 63) s_init[1 + wid] = incl;
        __syncthreads();
        int woff = 0, tot = 0;
#pragma unroll
        for (int w = 0; w < 4; w++) {
            int v = s_init[1 + w];
            if (w < wid) woff += v;
            tot += v;
        }
        int rm = s_init[0];
        int M = tot + ((rm < NPTS) ? 1 : 0);
        if (tid == 0) {
            st_wt_u32((unsigned*)&hdr[cblk * 2], (unsigned)M);
            st_wt_u32((unsigned*)&hdr[cblk * 2 + 1], (unsigned)((rm < NPTS) ? rm : -1));
        }
        if (M <= CCAP) {
            int pos = woff + incl - cnt;
            int rm_eff = (rm < NPTS) ? rm : 0x7fffffff;
#pragma unroll
            for (int c = 0; c < 8; c++) {
                if ((km >> (c * 4)) & 0xFu) {
                    float4 xx = *(const float4*)(xb + n0 + c * 4);
                    float4 yy = *(const float4*)(xb + NPTS + n0 + c * 4);
                    float4 zz = *(const float4*)(xb + 2 * NPTS + n0 + c * 4);
                    const float* xf = (const float*)&xx;
                    const float* yf = (const float*)&yy;
                    const float* zf = (const float*)&zz;
#pragma unroll
                    for (int j = 0; j < 4; j++) {
                        if ((km >> (c * 4 + j)) & 1u) {
                            int idx = n0 + c * 4 + j;
                            int fin = pos + ((idx > rm_eff) ? 1 : 0);
                            sc[fin] = make_float4(xf[j], yf[j], zf[j], 0.0f);
                            pos++;
                        }
                    }
                }
            }
            if (tid == 0 && rm < NPTS)   // rep zero-point at slot rm (idx<rm all kept)
                sc[rm] = make_float4(__fmul_rn(0.0f, xb[rm]),
                                     __fmul_rn(0.0f, xb[NPTS + rm]),
                                     __fmul_rn(0.0f, xb[2 * NPTS + rm]), 0.0f);
        }
        __syncthreads();                  // LDS scatter complete
        if (M <= CCAP) {
            unsigned long long* scu = (unsigned long long*)sc;
            unsigned long long* gcu =
                (unsigned long long*)(cxyz + (size_t)cblk * CCAP);
            int nU = ((M + 255) & ~255) * 2;   // u64 count, 512-aligned chunks
            for (int i = tid; i < nU; i += 256)
                st_wt_u64(&gcu[i], scu[i]);    // coalesced: 512 B/wave/inst
        }
        asm volatile("s_waitcnt vmcnt(0)" ::: "memory");   // per-wave drain
        __syncthreads();                                   // all waves drained
        if (tid == 0)
            __hip_atomic_store(&cflag[cblk], 1, __ATOMIC_RELAXED, __HIP_MEMORY_SCOPE_AGENT);
    } else if (blk < 32 + 1024) {
        // ---------------- points transpose (256 thr, 64x64 tile) ----------------
        float (*t)[65] = (float(*)[65])smem;
        int blk2 = blk - 32;
        int b = blk2 >> 7;
        int n0 = (blk2 & 127) * 64;
        int tx = tid & 63, ty = tid >> 6;      // ty in 0..3
        for (int c = ty; c < 64; c += 4)
            t[c][tx] = pts[((size_t)b * DFEAT + c) * NPTS + n0 + tx];
        __syncthreads();
        {
            unsigned* pTu = (unsigned*)ptsTh;
            int txc = tid & 31, rr = tid >> 5;   // 32 u32 cols x 8 row phases
            for (int r = rr; r < 64; r += 8) {
                unsigned lo = f2b(t[2 * txc][r]);
                unsigned hi = f2b(t[2 * txc + 1][r]);
                st_wt_u32(&pTu[((size_t)b * NPTS + n0 + r) * 32 + txc],
                          lo | (hi << 16));
            }
        }
        asm volatile("s_waitcnt vmcnt(0)" ::: "memory");   // per-wave drain
        __syncthreads();                                   // all waves drained
        if (tid == 0)
            __hip_atomic_fetch_add(tcount, 1, __ATOMIC_RELAXED, __HIP_MEMORY_SCOPE_AGENT);
    } else if (blk < 1092) {
        // ---------------- weight pack (all stores in wave 0) ----------------
        if (tid < 64) {
            int t = blk - (32 + 1024), l = tid;
            int kq = (l >> 4) * 8, n16 = l & 15;
            unsigned short o[8];
#pragma unroll
            for (int j = 0; j < 8; j++) {
                float v;
                if (t < 12) {
                    int kt = t >> 2, nt = t & 3;
                    int k = kt * 32 + kq + j, n = nt * 16 + n16;
                    v = (k < 64) ? w0[n * INCH + 3 + k] : (k < 67 ? w0[n * INCH + (k - 64)] : 0.0f);
                } else if (t < 20) {
                    int tt = t - 12, kt = tt >> 2, nt = tt & 3;
                    v = w1[(nt * 16 + n16) * 64 + kt * 32 + kq + j];
                } else {
                    int tt = t - 20, kt = tt >> 3, nt = tt & 7;
                    v = w2[(nt * 16 + n16) * 64 + kt * 32 + kq + j];
                }
                o[j] = f2b(v);
            }
            unsigned* wpu = (unsigned*)wp;
            size_t baseu = (size_t)t * 256 + l * 4;
#pragma unroll
            for (int j = 0; j < 4; j++)
                st_wt_u32(&wpu[baseu + j],
                          (unsigned)o[2 * j] | ((unsigned)o[2 * j + 1] << 16));
            asm volatile("s_waitcnt vmcnt(0)" ::: "memory");  // wave-0 drain
            if (tid == 0)
                __hip_atomic_fetch_add(tcount, 1, __ATOMIC_RELAXED, __HIP_MEMORY_SCOPE_AGENT);
        }
    } else {
        // ---------------- streamed ball+MLP consumers ----------------
        int lane = tid & 63, wid = tid >> 6;
        int w = (blk - 1092) * 4 + wid;        // production-ordered wave id
        int b, grp, kk;
        if (w < 2048) { kk = w >> 4; int r = w & 15; b = r & 7; grp = r >> 3; }
        else          { int w2 = w - 2048; kk = 128 + (w2 >> 3); b = w2 & 7; grp = 1; }
        int sg = (grp ? 128 : 0) + kk;
        int q = b * 512 + sg;
        int pblk = b * 2 + grp;

        // Bounded poll: 500 x s_sleep(64) ~ 2.0M cycles. Timeout/overflow ->
        // defer to cleanup.
        int ok = 1;
        for (int to = 0;;) {
            int p = __hip_atomic_load(&prog[pblk], __ATOMIC_RELAXED, __HIP_MEMORY_SCOPE_AGENT);
            if (p < 0) { ok = 0; break; }      // producer gave up -> fallback path
            if (p > kk) {
                int t = __hip_atomic_load(tcount, __ATOMIC_RELAXED, __HIP_MEMORY_SCOPE_AGENT);
                if (t >= TDONE) break;         // point + transposed feats + weights ready
            }
            if (++to > 500) { ok = 0; break; }
            __builtin_amdgcn_s_sleep(64);
        }
        if (!ok) {
            if (lane == 0) skip[q] = 1;        // visible to cleanup at kernel boundary
            return;
        }
        __builtin_amdgcn_fence(__ATOMIC_ACQUIRE, "agent");  // buffer_inv: fresh reads

        short* sBufW = (short*)(smem + wid * BALLW);
        int* s_idxW = (int*)(smem + wid * BALLW + 13312);
        ball_one(xyz, ptsTh, wp, b0v, b1v, b2v, out0, out1, b, sg, lane, sBufW, s_idxW);
    }
}

// ---------------------------------------------------------------------------
// CLEANUP kernel (R20/R21-verified): merges gated FPS fallback + ball tail.
//   blocks 0..15 : full-input FPS fallback, gated on (fpsdone==0 || M>CCAP).
//                  ALL 16 blocks increment fpsfb when done (gated or not).
//   blocks 16..79: ball for skipped q's. Fast path (no skips) exits without
//                  waiting. Slow path waits fpsfb==16 (all blocks co-resident
//                  -> guaranteed progress, bounded poll -> no hang).
// ---------------------------------------------------------------------------
__global__ __launch_bounds__(1024, 1) void cleanup(
    const float* __restrict__ xyz, const float* __restrict__ attn,
    const int* __restrict__ hdr,
    float* __restrict__ out0, float* __restrict__ out2,
    const unsigned short* __restrict__ ptsTh,
    const unsigned short* __restrict__ wp,
    const float* __restrict__ b0, const float* __restrict__ b1,
    const float* __restrict__ b2,
    float* __restrict__ out1,
    const int* __restrict__ skip,
    const int* __restrict__ fpsdone, int* __restrict__ fpsfb)
{
    __shared__ __align__(16) char smem[4 * BALLW];   // 54272 B union
    int blk = blockIdx.x;
    int tid = threadIdx.x;

    if (blk < 16) {
        // ---------------- gated FPS fallback (fps_kernel body) ----------------
        int need = (fpsdone[blk] == 0) || (hdr[blk * 2] > CCAP);
        if (!need) {
            if (tid == 0)
                __hip_atomic_fetch_add(fpsfb, 1, __ATOMIC_RELAXED, __HIP_MEMORY_SCOPE_AGENT);
            return;
        }
        unsigned long long* s_red = (unsigned long long*)smem;   // [2][16]
        int b = blk >> 1, grp = blk & 1;
        int K = grp ? 384 : 128;
        int soff = grp ? 128 : 0;
        int lane = tid & 63, wid = tid >> 6;
        const float* xb = xyz + (size_t)b * 3 * NPTS;
        const float* ab = attn + (size_t)b * NPTS;

        float px[8], py[8], pz[8], md[8];
#pragma unroll
        for (int i = 0; i < 8; i++) {
            int n = tid + i * 1024;
            float a = ab[n];
            float f = grp ? __fsub_rn(1.0f, a) : a;
            px[i] = __fmul_rn(f, xb[n]);
            py[i] = __fmul_rn(f, xb[NPTS + n]);
            pz[i] = __fmul_rn(f, xb[2 * NPTS + n]);
            md[i] = 1e10f;
        }
        float a_last = ab[0];
        float f0 = grp ? __fsub_rn(1.0f, a_last) : a_last;
        float lx = __fmul_rn(f0, xb[0]);
        float ly = __fmul_rn(f0, xb[NPTS]);
        float lz = __fmul_rn(f0, xb[2 * NPTS]);

        for (int k = 0; k < K; k++) {
            if (tid == 0) {
                int sg = soff + k;
                out0[(size_t)b * 3 * S_TOT + sg] = lx;
                out0[(size_t)b * 3 * S_TOT + S_TOT + sg] = ly;
                out0[(size_t)b * 3 * S_TOT + 2 * S_TOT + sg] = lz;
                out2[(size_t)b * S_TOT + sg] = a_last;
            }
            if (k == K - 1) break;
            float bv = -1.0f; int bi = 0;
#pragma unroll
            for (int i = 0; i < 8; i++) {
                float d2 = d2_exact(px[i], py[i], pz[i], lx, ly, lz);
                md[i] = fminf(md[i], d2);
                if (md[i] > bv) { bv = md[i]; bi = tid + i * 1024; }
            }
            unsigned long long best =
                ((unsigned long long)__float_as_uint(bv) << 32) | (unsigned)(~bi);
#pragma unroll
            for (int off = 32; off >= 1; off >>= 1) {
                unsigned long long o = __shfl_down(best, off);
                best = (o > best) ? o : best;
            }
            if (lane == 0) s_red[(k & 1) * 16 + wid] = best;
            __syncthreads();
            unsigned long long r = (lane < 16) ? s_red[(k & 1) * 16 + lane] : 0ull;
#pragma unroll
            for (int off = 8; off >= 1; off >>= 1) {
                unsigned long long o = __shfl_down(r, off);
                r = (o > r) ? o : r;
            }
            r = __shfl(r, 0);
            int n = (int)(~(unsigned)r);
            a_last = ab[n];
            float fl = grp ? __fsub_rn(1.0f, a_last) : a_last;
            lx = __fmul_rn(fl, xb[n]);
            ly = __fmul_rn(fl, xb[NPTS + n]);
            lz = __fmul_rn(fl, xb[2 * NPTS + n]);
        }
        __syncthreads();
        if (tid == 0) {
            __builtin_amdgcn_fence(__ATOMIC_RELEASE, "agent");   // pathological path only
            __hip_atomic_fetch_add(fpsfb, 1, __ATOMIC_RELAXED, __HIP_MEMORY_SCOPE_AGENT);
        }
    } else {
        // ---------------- ball for skipped q's ----------------
        if (tid >= 256) return;
        int lane = tid & 63, wid = tid >> 6;
        int q0 = ((blk - 16) * 4 + wid) * 16;
        int any = 0;
#pragma unroll 1
        for (int i = 0; i < 16; i++) any |= skip[q0 + i];
        if (!any) return;                                        // fast path
        for (int to = 0; to < 4000; ++to) {                      // wait FPS redo
            if (__hip_atomic_load(fpsfb, __ATOMIC_RELAXED, __HIP_MEMORY_SCOPE_AGENT) >= 16) break;
            __builtin_amdgcn_s_sleep(64);
        }
        __builtin_amdgcn_fence(__ATOMIC_ACQUIRE, "agent");
        short* sBufW = (short*)(smem + wid * BALLW);
        int* s_idxW = (int*)(smem + wid * BALLW + 13312);
#pragma unroll 1
        for (int i = 0; i < 16; i++) {
            int q = q0 + i;
            if (skip[q] == 0) continue;
            int b = q >> 9, sg = q & 511;
            ball_one(xyz, ptsTh, wp, b0, b1, b2, out0, out1, b, sg, lane, sBufW, s_idxW);
        }
    }
}

// ---------------------------------------------------------------------------
// Fallback FPS for the small-ws path (hdr==nullptr -> always runs).
// ---------------------------------------------------------------------------
__global__ __launch_bounds__(1024, 1) void fps_kernel(
    const float* __restrict__ xyz, const float* __restrict__ attn,
    const int* __restrict__ hdr,
    float* __restrict__ out0, float* __restrict__ out2)
{
    int blk = blockIdx.x;
    if (hdr != nullptr && hdr[blk * 2] <= CCAP) return;
    int b = blk >> 1, grp = blk & 1;
    int K = grp ? 384 : 128;
    int soff = grp ? 128 : 0;
    int tid = threadIdx.x, lane = tid & 63, wid = tid >> 6;
    const float* xb = xyz + (size_t)b * 3 * NPTS;
    const float* ab = attn + (size_t)b * NPTS;

    float px[8], py[8], pz[8], md[8];
#pragma unroll
    for (int i = 0; i < 8; i++) {
        int n = tid + i * 1024;
        float a = ab[n];
        float f = grp ? __fsub_rn(1.0f, a) : a;
        px[i] = __fmul_rn(f, xb[n]);
        py[i] = __fmul_rn(f, xb[NPTS + n]);
        pz[i] = __fmul_rn(f, xb[2 * NPTS + n]);
        md[i] = 1e10f;
    }
    __shared__ unsigned long long s_red[2][16];
    float a_last = ab[0];
    float f0 = grp ? __fsub_rn(1.0f, a_last) : a_last;
    float lx = __fmul_rn(f0, xb[0]);
    float ly = __fmul_rn(f0, xb[NPTS]);
    float lz = __fmul_rn(f0, xb[2 * NPTS]);

    for (int k = 0; k < K; k++) {
        if (tid == 0) {
            int sg = soff + k;
            out0[(size_t)b * 3 * S_TOT + sg] = lx;
            out0[(size_t)b * 3 * S_TOT + S_TOT + sg] = ly;
            out0[(size_t)b * 3 * S_TOT + 2 * S_TOT + sg] = lz;
            out2[(size_t)b * S_TOT + sg] = a_last;
        }
        if (k == K - 1) break;
        float bv = -1.0f; int bi = 0;
#pragma unroll
        for (int i = 0; i < 8; i++) {
            float d2 = d2_exact(px[i], py[i], pz[i], lx, ly, lz);
            md[i] = fminf(md[i], d2);
            if (md[i] > bv) { bv = md[i]; bi = tid + i * 1024; }
        }
        unsigned long long best =
            ((unsigned long long)__float_as_uint(bv) << 32) | (unsigned)(~bi);
#pragma unroll
        for (int off = 32; off >= 1; off >>= 1) {
            unsigned long long o = __shfl_down(best, off);
            best = (o > best) ? o : best;
        }
        if (lane == 0) s_red[k & 1][wid] = best;
        __syncthreads();
        unsigned long long r = (lane < 16) ? s_red[k & 1][lane] : 0ull;
#pragma unroll
        for (int off = 8; off >= 1; off >>= 1) {
            unsigned long long o = __shfl_down(r, off);
            r = (o > r) ? o : r;
        }
        r = __shfl(r, 0);
        int n = (int)(~(unsigned)r);
        a_last = ab[n];
        float fl = grp ? __fsub_rn(1.0f, a_last) : a_last;
        lx = __fmul_rn(fl, xb[n]);
        ly = __fmul_rn(fl, xb[NPTS + n]);
        lz = __fmul_rn(fl, xb[2 * NPTS + n]);
    }
}

// ---------------------------------------------------------------------------
// Fallback ball+MLP (no ws): unchanged from R6.
// ---------------------------------------------------------------------------
__global__ __launch_bounds__(64, 1) void ball_mlp_fb(
    const float* __restrict__ xyz, const float* __restrict__ pts,
    const float* __restrict__ w0, const float* __restrict__ b0,
    const float* __restrict__ w1, const float* __restrict__ b1,
    const float* __restrict__ w2, const float* __restrict__ b2,
    const float* __restrict__ out0, float* __restrict__ out1)
{
    const float R2 = (float)(0.4 * 0.4);
    int q = blockIdx.x;
    int b = q >> 9, sg = q & 511, lane = threadIdx.x;
    const float* xb = xyz + (size_t)b * 3 * NPTS;
    float qx = out0[(size_t)b * 3 * S_TOT + sg];
    float qy = out0[(size_t)b * 3 * S_TOT + S_TOT + sg];
    float qz = out0[(size_t)b * 3 * S_TOT + 2 * S_TOT + sg];

    __shared__ int s_idx[NSAMP];
    __shared__ float s_h[32 * 64];
    int cnt = 0;
    for (int base = 0; base < NPTS; base += 64) {
        int n = base + lane;
        float d2 = d2_exact(qx, qy, qz, xb[n], xb[NPTS + n], xb[2 * NPTS + n]);
        bool flag = d2 < R2;
        unsigned long long m = __ballot(flag);
        int pos = cnt + (int)__popcll(m & ((1ull << lane) - 1ull));
        if (flag && pos < NSAMP) s_idx[pos] = n;
        cnt += (int)__popcll(m);
    }
    if (cnt > NSAMP) cnt = NSAMP;
    int nb = (lane < cnt) ? s_idx[lane] : -1;
    float nx_ = 0.f, ny_ = 0.f, nz_ = 0.f;
    if (nb >= 0) { nx_ = xb[nb]; ny_ = xb[NPTS + nb]; nz_ = xb[2 * NPTS + nb]; }
    float fx = nx_ - qx, fy = ny_ - qy, fz = nz_ - qz;
    int row = (nb < 0) ? (NPTS - 1) : nb;

    float h1[64];
#pragma unroll
    for (int o = 0; o < 64; o++) {
        float a = __builtin_fmaf(w0[o * INCH + 0], fx, b0[o]);
        a = __builtin_fmaf(w0[o * INCH + 1], fy, a);
        h1[o] = __builtin_fmaf(w0[o * INCH + 2], fz, a);
    }
    const float* pb = pts + (size_t)b * DFEAT * NPTS + row;
#pragma unroll 1
    for (int c = 0; c < 64; c++) {
        float f = pb[(size_t)c * NPTS];
#pragma unroll
        for (int o = 0; o < 64; o++)
            h1[o] = __builtin_fmaf(w0[o * INCH + 3 + c], f, h1[o]);
    }
#pragma unroll
    for (int c = 0; c < 32; c++) s_h[c * 64 + lane] = fmaxf(h1[c], 0.0f);
    float h1h[32];
#pragma unroll
    for (int c = 0; c < 32; c++) h1h[c] = fmaxf(h1[32 + c], 0.0f);

    float h2[64];
#pragma unroll
    for (int o = 0; o < 64; o++) h2[o] = b1[o];
#pragma unroll 1
    for (int c = 0; c < 32; c++) {
        float hc = s_h[c * 64 + lane];
#pragma unroll
        for (int o = 0; o < 64; o++)
            h2[o] = __builtin_fmaf(w1[o * 64 + c], hc, h2[o]);
    }
#pragma unroll
    for (int c = 0; c < 32; c++) s_h[c * 64 + lane] = h1h[c];
#pragma unroll 1
    for (int c = 0; c < 32; c++) {
        float hc = s_h[c * 64 + lane];
#pragma unroll
        for (int o = 0; o < 64; o++)
            h2[o] = __builtin_fmaf(w1[o * 64 + (32 + c)], hc, h2[o]);
    }
#pragma unroll
    for (int o = 0; o < 64; o++) h2[o] = fmaxf(h2[o], 0.0f);

#pragma unroll 2
    for (int o = 0; o < 128; o++) {
        const float* wr = w2 + o * 64;
        float acc = b2[o];
#pragma unroll
        for (int c = 0; c < 64; c++) acc = __builtin_fmaf(wr[c], h2[c], acc);
        acc = fmaxf(acc, 0.0f);
#pragma unroll
        for (int off = 32; off >= 1; off >>= 1)
            acc = fmaxf(acc, __shfl_down(acc, off));
        if (lane == 0) out1[((size_t)(b * 128 + o)) * S_TOT + sg] = acc;
    }
}

extern "C" void kernel_launch(void* const* d_in, const int* in_sizes, int n_in,
                              void* d_out, int out_size, void* d_ws, size_t ws_size,
                              hipStream_t stream) {
    const float* xyz  = (const float*)d_in[0];
    const float* pts  = (const float*)d_in[1];
    const float* attn = (const float*)d_in[2];
    const float* w0 = (const float*)d_in[3];
    const float* b0 = (const float*)d_in[4];
    const float* w1 = (const float*)d_in[5];
    const float* b1 = (const float*)d_in[6];
    const float* w2 = (const float*)d_in[7];
    const float* b2 = (const float*)d_in[8];

    float* out0 = (float*)d_out;                    // [B,3,S]
    float* out1 = out0 + (size_t)NB * 3 * S_TOT;    // [B,128,S]
    float* out2 = out1 + (size_t)NB * 128 * S_TOT;  // [B,1,S]

    // ws: wp | ptsTh | cxyz | hdr | prog/tcnt/skip/fpsdn/fpsfb/cflag
    unsigned short* wp    = (unsigned short*)d_ws;
    unsigned short* ptsTh = (unsigned short*)((char*)d_ws + 36864);
    float4*         cxyz  = (float4*)((char*)d_ws + 36864 + 8388608);
    int*            hdr   = (int*)((char*)cxyz + (size_t)16 * CCAP * 16);
    int*            prog  = hdr + 32;        // 16 ints
    int*            tcnt  = prog + 16;       // 4 ints
    int*            skip  = tcnt + 4;        // 4096 ints
    int*            fpsdn = skip + 4096;     // 16 ints
    int*            fpsfb = fpsdn + 16;      // 16 ints (1 used)
    int*            cflag = fpsfb + 16;      // 16 ints
    const size_t ctrl_bytes = (size_t)(16 + 4 + 4096 + 16 + 16 + 16) * 4;
    const size_t need = 36864 + 8388608 + (size_t)16 * CCAP * 16 + 128
                        + ctrl_bytes + 64;

    if (ws_size >= need) {
        hipMemsetAsync(prog, 0, ctrl_bytes, stream);   // control words (capture-proven)
        fps_fused<<<16 + 16 + 1024 + 36 + 1024, 256, 0, stream>>>(
            attn, cxyz, hdr, out0, out2, pts, ptsTh, w0, w1, w2, wp,
            xyz, b0, b1, b2, out1, prog, tcnt, skip, fpsdn, cflag);
        cleanup<<<80, 1024, 0, stream>>>(xyz, attn, hdr, out0, out2, ptsTh, wp,
                                         b0, b1, b2, out1, skip, fpsdn, fpsfb);
    } else {
        fps_kernel<<<16, 1024, 0, stream>>>(xyz, attn, nullptr, out0, out2);
        ball_mlp_fb<<<NB * S_TOT, 64, 0, stream>>>(xyz, pts, w0, b0, w1, b1,
                                                   w2, b2, out0, out1);
    }
}

// Round 11
// 571.201 us; speedup vs baseline: 1.0076x; 1.0076x over previous
//
#include <hip/hip_runtime.h>
#include <cstdint>
#include <cstddef>

#define NB 8
#define NPTS 8192
#define S_TOT 512
#define NSAMP 64
#define DFEAT 64
#define INCH 67
#define SLOTS 17
#define CCAP (SLOTS * 256)   // 4352 compacted slots per (b,grp)
#define TDONE 1060           // 1024 transpose + 36 pack completions
#define BALLW 13568          // per-wave LDS slice for ball path (13312 sBuf + 256 s_idx)
#define SMEMSZ 82048         // > 81920 => 1 block/CU: FPS CUs host nothing else

typedef __attribute__((ext_vector_type(8))) short v8s;
typedef __attribute__((ext_vector_type(4))) short v4s;
typedef __attribute__((ext_vector_type(4))) float v4f;

// exact (numpy-matching) squared distance: (a-b) per component, square, sum as (x+y)+z
__device__ __forceinline__ float d2_exact(float ax, float ay, float az,
                                          float bx, float by, float bz) {
    float dx = __fsub_rn(ax, bx);
    float dy = __fsub_rn(ay, by);
    float dz = __fsub_rn(az, bz);
    return __fadd_rn(__fadd_rn(__fmul_rn(dx, dx), __fmul_rn(dy, dy)), __fmul_rn(dz, dz));
}

// fp32 -> bf16 round-to-nearest-even
__device__ __forceinline__ unsigned short f2b(float f) {
    unsigned u = __float_as_uint(f);
    return (unsigned short)((u + 0x7fffu + ((u >> 16) & 1u)) >> 16);
}

// write-through (coherent) store helpers: land at LLC, never dirty in L2.
__device__ __forceinline__ void st_wt_f32(float* p, float v) {
    __hip_atomic_store(p, v, __ATOMIC_RELAXED, __HIP_MEMORY_SCOPE_AGENT);
}
__device__ __forceinline__ void st_wt_u32(unsigned* p, unsigned v) {
    __hip_atomic_store(p, v, __ATOMIC_RELAXED, __HIP_MEMORY_SCOPE_AGENT);
}

template <int CTRL>
__device__ __forceinline__ unsigned long long dpp_max_u64(unsigned long long k) {
    int lo = (int)(unsigned)(k & 0xffffffffull);
    int hi = (int)(unsigned)(k >> 32);
    int slo = __builtin_amdgcn_update_dpp(lo, lo, CTRL, 0xf, 0xf, false);
    int shi = __builtin_amdgcn_update_dpp(hi, hi, CTRL, 0xf, 0xf, false);
    unsigned long long o = ((unsigned long long)(unsigned)shi << 32) | (unsigned)slo;
    return (o > k) ? o : k;
}

// ---------------------------------------------------------------------------
// Ball query + MFMA MLP + max for ONE query point, one wave (R10-verified
// body, absmax 0.015625). LDS comes in as a per-wave slice.
// ---------------------------------------------------------------------------
__device__ __forceinline__ void ball_one(
    const float* __restrict__ xyz,
    const unsigned short* __restrict__ ptsTh,
    const unsigned short* __restrict__ wp,
    const float* __restrict__ b0, const float* __restrict__ b1,
    const float* __restrict__ b2,
    const float* __restrict__ out0, float* __restrict__ out1,
    int b, int sg, int lane, short* sBuf, int* s_idx)
{
    const float R2 = (float)(0.4 * 0.4);   // 0x3E23D70A — NOT 0.4f*0.4f
    int col = lane & 15, quad = lane >> 4, kq = quad * 8;

    const float* xb = xyz + (size_t)b * 3 * NPTS;
    float qx = out0[(size_t)b * 3 * S_TOT + sg];
    float qy = out0[(size_t)b * 3 * S_TOT + S_TOT + sg];
    float qz = out0[(size_t)b * 3 * S_TOT + 2 * S_TOT + sg];

    unsigned long long* s_mask = (unsigned long long*)sBuf;  // phase A: 1 KB

    // ---- phase 1: independent ballots ----
#pragma unroll 8
    for (int j = 0; j < 128; j++) {
        int n = j * 64 + lane;
        float d2 = d2_exact(qx, qy, qz, xb[n], xb[NPTS + n], xb[2 * NPTS + n]);
        unsigned long long m = __ballot(d2 < R2);
        if (lane == 0) s_mask[j] = m;
    }

    // ---- phase 2: prefix over 128 chunk popcounts ----
    unsigned long long m0 = s_mask[lane];
    unsigned long long m1 = s_mask[64 + lane];
    int c0 = (int)__popcll(m0), c1 = (int)__popcll(m1);
    int i0 = c0;
#pragma unroll
    for (int off = 1; off <= 32; off <<= 1) {
        int t = __shfl_up(i0, off);
        if (lane >= off) i0 += t;
    }
    int T0 = __shfl(i0, 63);
    int i1 = c1;
#pragma unroll
    for (int off = 1; off <= 32; off <<= 1) {
        int t = __shfl_up(i1, off);
        if (lane >= off) i1 += t;
    }
    int total = T0 + __shfl(i1, 63);
    int p0 = i0 - c0;
    int p1 = T0 + i1 - c1;

    // ---- phase 3: bit expansion into s_idx (global chunk/bit order) ----
    {
        int base = p0, org = lane * 64;
        while (m0 && base < NSAMP) {
            int bp = __ffsll((long long)m0) - 1;
            s_idx[base++] = org + bp;
            m0 &= m0 - 1;
        }
        base = p1; org = (64 + lane) * 64;
        while (m1 && base < NSAMP) {
            int bp = __ffsll((long long)m1) - 1;
            s_idx[base++] = org + bp;
            m1 &= m1 - 1;
        }
    }
    int cnt = (total > NSAMP) ? NSAMP : total;

    int nb = (lane < cnt) ? s_idx[lane] : -1;
    float nx_ = 0.f, ny_ = 0.f, nz_ = 0.f;
    if (nb >= 0) { nx_ = xb[nb]; ny_ = xb[NPTS + nb]; nz_ = xb[2 * NPTS + nb]; }
    float fx = nx_ - qx, fy = ny_ - qy, fz = nz_ - qz;   // pad rows: -new_xyz
    int row = (nb < 0) ? (NPTS - 1) : nb;                // torch -1 wraps to last

    // ---- stage X1 row (stride 104; masks dead, safe to overwrite) ----
    {
        const unsigned short* ph = ptsTh + ((size_t)b * NPTS + row) * DFEAT;
        short* xr = &sBuf[lane * 104];
#pragma unroll
        for (int i = 0; i < 8; i++)
            *(v8s*)(xr + i * 8) = *(const v8s*)(ph + i * 8);
#pragma unroll
        for (int i = 0; i < 5; i++)
            *(v8s*)(xr + 64 + i * 8) = (v8s)0;
        v4s xyzp;
        xyzp[0] = (short)f2b(fx); xyzp[1] = (short)f2b(fy);
        xyzp[2] = (short)f2b(fz); xyzp[3] = 0;
        *(v4s*)(xr + 64) = xyzp;
    }

    const v8s* wpv = (const v8s*)wp;

    // ---- layer 1: [64x96] x [96x64], 3 K-steps ----
    v4f acc[4][4];
#pragma unroll
    for (int nt = 0; nt < 4; nt++) {
        float bb = b0[nt * 16 + col];
#pragma unroll
        for (int mt = 0; mt < 4; mt++) acc[mt][nt] = (v4f){bb, bb, bb, bb};
    }
#pragma unroll
    for (int kt = 0; kt < 3; kt++) {
        v8s bf[4];
#pragma unroll
        for (int nt = 0; nt < 4; nt++) bf[nt] = wpv[(kt * 4 + nt) * 64 + lane];
#pragma unroll
        for (int mt = 0; mt < 4; mt++) {
            v8s a = *(const v8s*)&sBuf[(mt * 16 + col) * 104 + kt * 32 + kq];
#pragma unroll
            for (int nt = 0; nt < 4; nt++)
                acc[mt][nt] = __builtin_amdgcn_mfma_f32_16x16x32_bf16(a, bf[nt], acc[mt][nt], 0, 0, 0);
        }
    }
#pragma unroll
    for (int mt = 0; mt < 4; mt++)
#pragma unroll
        for (int nt = 0; nt < 4; nt++)
#pragma unroll
            for (int r = 0; r < 4; r++)
                sBuf[(mt * 16 + quad * 4 + r) * 72 + nt * 16 + col] =
                    (short)f2b(fmaxf(acc[mt][nt][r], 0.0f));

    // ---- layer 2: [64x64] x [64x64], 2 K-steps ----
#pragma unroll
    for (int nt = 0; nt < 4; nt++) {
        float bb = b1[nt * 16 + col];
#pragma unroll
        for (int mt = 0; mt < 4; mt++) acc[mt][nt] = (v4f){bb, bb, bb, bb};
    }
#pragma unroll
    for (int kt = 0; kt < 2; kt++) {
        v8s bf[4];
#pragma unroll
        for (int nt = 0; nt < 4; nt++) bf[nt] = wpv[(12 + kt * 4 + nt) * 64 + lane];
#pragma unroll
        for (int mt = 0; mt < 4; mt++) {
            v8s a = *(const v8s*)&sBuf[(mt * 16 + col) * 72 + kt * 32 + kq];
#pragma unroll
            for (int nt = 0; nt < 4; nt++)
                acc[mt][nt] = __builtin_amdgcn_mfma_f32_16x16x32_bf16(a, bf[nt], acc[mt][nt], 0, 0, 0);
        }
    }
#pragma unroll
    for (int mt = 0; mt < 4; mt++)
#pragma unroll
        for (int nt = 0; nt < 4; nt++)
#pragma unroll
            for (int r = 0; r < 4; r++)
                sBuf[(mt * 16 + quad * 4 + r) * 72 + nt * 16 + col] =
                    (short)f2b(fmaxf(acc[mt][nt][r], 0.0f));

    // ---- layer 3: [64x64] x [64x128], two passes of 4 N-tiles ----
#pragma unroll
    for (int p = 0; p < 2; p++) {
#pragma unroll
        for (int nt = 0; nt < 4; nt++) {
            float bb = b2[(p * 4 + nt) * 16 + col];
#pragma unroll
            for (int mt = 0; mt < 4; mt++) acc[mt][nt] = (v4f){bb, bb, bb, bb};
        }
#pragma unroll
        for (int kt = 0; kt < 2; kt++) {
            v8s bf[4];
#pragma unroll
            for (int nt = 0; nt < 4; nt++)
                bf[nt] = wpv[(20 + kt * 8 + p * 4 + nt) * 64 + lane];
#pragma unroll
            for (int mt = 0; mt < 4; mt++) {
                v8s a = *(const v8s*)&sBuf[(mt * 16 + col) * 72 + kt * 32 + kq];
#pragma unroll
                for (int nt = 0; nt < 4; nt++)
                    acc[mt][nt] = __builtin_amdgcn_mfma_f32_16x16x32_bf16(a, bf[nt], acc[mt][nt], 0, 0, 0);
            }
        }
#pragma unroll
        for (int nt = 0; nt < 4; nt++) {
            float v = 0.0f;   // relu output >= 0
#pragma unroll
            for (int mt = 0; mt < 4; mt++)
#pragma unroll
                for (int r = 0; r < 4; r++)
                    v = fmaxf(v, acc[mt][nt][r]);
            v = fmaxf(v, __shfl_xor(v, 16));
            v = fmaxf(v, __shfl_xor(v, 32));
            if (lane < 16)
                out1[((size_t)(b * 128 + (p * 4 + nt) * 16 + lane)) * S_TOT + sg] = v;
        }
    }
}

// ---------------------------------------------------------------------------
// Compact (R5-R12-verified, 1024-thr, normal cached stores) + zero-init of
// streaming control words (prog/tcnt/skip/fpsdn/fpsfb).
// ---------------------------------------------------------------------------
__global__ __launch_bounds__(1024) void fps_compact(
    const float* __restrict__ xyz, const float* __restrict__ attn,
    float4* __restrict__ cxyz, int* __restrict__ hdr,
    int* __restrict__ prog, int* __restrict__ tcount, int* __restrict__ skip,
    int* __restrict__ fpsdn, int* __restrict__ fpsfb)
{
    int blk = blockIdx.x;
    int tid = threadIdx.x;
    if (blk == 0) {                       // control-word init for the fused stream
        if (tid < 16) prog[tid] = 0;
        if (tid == 16) tcount[0] = 0;
        if (tid >= 32 && tid < 48) fpsdn[tid - 32] = 0;
        if (tid >= 48 && tid < 64) fpsfb[tid - 48] = 0;
        ((int4*)skip)[tid] = make_int4(0, 0, 0, 0);   // 4096 ints = 1024 int4
    }
    int b = blk >> 1, grp = blk & 1;
    const float* xb = xyz + (size_t)b * 3 * NPTS;
    const float* ab = attn + (size_t)b * NPTS;
    float4* c4 = cxyz + (size_t)blk * CCAP;

    int lane = tid & 63, wid = tid >> 6;
    int n0 = tid * 8;

    __shared__ int s_repmin;
    __shared__ int s_ws[16];
    if (tid == 0) s_repmin = NPTS;
    __syncthreads();

    float av[8];
    *(float4*)&av[0] = *(const float4*)(ab + n0);
    *(float4*)&av[4] = *(const float4*)(ab + n0 + 4);
    int cnt = 0, mymin = NPTS;
    bool keep[8];
#pragma unroll
    for (int j = 0; j < 8; j++) {
        keep[j] = grp ? (av[j] == 0.0f) : (av[j] != 0.0f);
        cnt += keep[j] ? 1 : 0;
        if (!keep[j] && n0 + j < mymin) mymin = n0 + j;
    }
    if (mymin < NPTS) atomicMin(&s_repmin, mymin);

    int incl = cnt;
#pragma unroll
    for (int off = 1; off <= 32; off <<= 1) {
        int t = __shfl_up(incl, off);
        if (lane >= off) incl += t;
    }
    if (lane == 63) s_ws[wid] = incl;
    __syncthreads();
    int woff = 0, tot = 0;
#pragma unroll
    for (int w = 0; w < 16; w++) { if (w < wid) woff += s_ws[w]; tot += s_ws[w]; }
    int pos = woff + incl - cnt;
    int rm = s_repmin;
    int rm_eff = (rm < NPTS) ? rm : 0x7fffffff;

    float xv[8], yv[8], zv[8];
    *(float4*)&xv[0] = *(const float4*)(xb + n0);
    *(float4*)&xv[4] = *(const float4*)(xb + n0 + 4);
    *(float4*)&yv[0] = *(const float4*)(xb + NPTS + n0);
    *(float4*)&yv[4] = *(const float4*)(xb + NPTS + n0 + 4);
    *(float4*)&zv[0] = *(const float4*)(xb + 2 * NPTS + n0);
    *(float4*)&zv[4] = *(const float4*)(xb + 2 * NPTS + n0 + 4);
#pragma unroll
    for (int j = 0; j < 8; j++) {
        if (keep[j]) {
            int fin = pos + ((n0 + j > rm_eff) ? 1 : 0);
            if (fin < CCAP)
                c4[fin] = make_float4(xv[j], yv[j], zv[j], 0.0f);
            pos++;
        }
    }
    if (tid == 0) {
        int M = tot;
        if (rm < NPTS) {
            if (rm < CCAP)
                c4[rm] = make_float4(__fmul_rn(0.0f, xb[rm]),
                                     __fmul_rn(0.0f, xb[NPTS + rm]),
                                     __fmul_rn(0.0f, xb[2 * NPTS + rm]), 0.0f);
            M++;
        }
        hdr[blk * 2] = M;
        hdr[blk * 2 + 1] = (rm < NPTS) ? rm : -1;
    }
}

// ---------------------------------------------------------------------------
// FUSED streaming kernel (R19-exact; + fpsdone publish for cleanup gate).
//   blocks 0..15     : fps_iter (R10 loop, raw lgkm-only barriers) +
//                      deferred per-16-iter flush/publish
//   blocks 16..1039  : points transpose (+tcount)
//   blocks 1040..1075: weight pack (+tcount)
//   blocks 1076..2099: ball+MLP consumers (production order).
// LDS 82048 B => 1 block/CU: FPS CUs host nothing else (R19: −17 us).
// ---------------------------------------------------------------------------
__global__ __launch_bounds__(256, 1) void fps_fused(
    const float* __restrict__ attn,
    const float4* __restrict__ cxyz,
    const int* __restrict__ hdr,
    float* __restrict__ out0, float* __restrict__ out2,
    const float* __restrict__ pts, unsigned short* __restrict__ ptsTh,
    const float* __restrict__ w0, const float* __restrict__ w1,
    const float* __restrict__ w2, unsigned short* __restrict__ wp,
    const float* __restrict__ xyz,
    const float* __restrict__ b0v, const float* __restrict__ b1v,
    const float* __restrict__ b2v,
    float* __restrict__ out1,
    int* __restrict__ prog, int* __restrict__ tcount, int* __restrict__ skip,
    int* __restrict__ fpsdone)
{
    __shared__ __align__(16) char smem[SMEMSZ];   // 82048 B => 1 block/CU
    int blk = blockIdx.x;
    int tid = threadIdx.x;

    if (blk < 16) {
        // ---------------- fps_iter (R10-exact) + deferred streaming flush ----------------
        int b = blk >> 1, grp = blk & 1;
        int K = grp ? 384 : 128;
        int soff = grp ? 128 : 0;
        int M = hdr[blk * 2];
        int repslot = hdr[blk * 2 + 1];
        if (M > CCAP) {                   // cleanup fallback covers this block
            if (tid == 0)
                __hip_atomic_store(&prog[blk], -1, __ATOMIC_RELAXED, __HIP_MEMORY_SCOPE_AGENT);
            return;
        }
        int lane = tid & 63, wid = tid >> 6;
        __builtin_amdgcn_s_setprio(1);

        const float4* cb = cxyz + (size_t)blk * CCAP;
        float4* sc = (float4*)smem;                                   // [CCAP]
        float4* s_obuf = (float4*)(smem + 69632);                     // [384]
        unsigned long long* s_red = (unsigned long long*)(smem + 69632 + 6144); // [2][4]

        float px[SLOTS], py[SLOTS], pz[SLOTS], md[SLOTS];
#pragma unroll
        for (int i = 0; i < SLOTS; i++) {
            int sl = i * 256 + tid;
            bool v = sl < M;
            float4 c = v ? cb[sl] : make_float4(0.f, 0.f, 0.f, 0.f);
            px[i] = c.x; py[i] = c.y; pz[i] = c.z;
            sc[sl] = c;
            md[i] = v ? 1e10f : -1.0f;
        }
        float4 c0 = cb[0];
        float lx = c0.x, ly = c0.y, lz = c0.z;
        float a_last = attn[(size_t)b * NPTS];
        float kept_a = grp ? 0.0f : 1.0f;
        float rep_a  = grp ? 1.0f : 0.0f;
        __syncthreads();                  // staging visible (full drain OK here, once)

        for (int k = 0; k < K; k++) {
            if (tid == 0) s_obuf[k] = make_float4(lx, ly, lz, a_last);
            if (k == K - 1) break;

            float bv = -1.0f; int bslot = 0x7fffffff;
#pragma unroll
            for (int i = 0; i < SLOTS; i++) {
                float d2 = d2_exact(px[i], py[i], pz[i], lx, ly, lz);
                md[i] = fminf(md[i], d2);
                int sl = i * 256 + tid;
                bool w = (md[i] > bv) || ((md[i] == bv) && (sl < bslot));
                bv = w ? md[i] : bv;
                bslot = w ? sl : bslot;
            }
            unsigned long long key = (bv >= 0.0f)
                ? (((unsigned long long)__float_as_uint(bv) << 32) | (unsigned)(~bslot))
                : 0ull;
            key = dpp_max_u64<0x111>(key);
            key = dpp_max_u64<0x112>(key);
            key = dpp_max_u64<0x114>(key);
            key = dpp_max_u64<0x118>(key);
            key = dpp_max_u64<0x142>(key);
            key = dpp_max_u64<0x143>(key);    // lane 63 = wave max
            int buf = k & 1;
            if (lane == 63) s_red[buf * 4 + wid] = key;
            // raw barrier: LDS-only drain; wave 3's publish stores stay in flight.
            asm volatile("s_waitcnt lgkmcnt(0)\n\ts_barrier" ::: "memory");
            __builtin_amdgcn_sched_barrier(0);

            const unsigned long long* rp = &s_red[buf * 4];
            unsigned long long k0 = rp[0], k1 = rp[1], k2 = rp[2], k3 = rp[3];
            unsigned long long m01 = (k0 > k1) ? k0 : k1;
            unsigned long long m23 = (k2 > k3) ? k2 : k3;
            unsigned long long g = (m01 > m23) ? m01 : m23;
            int wslot = (int)(~(unsigned)g);
            float4 wc = sc[wslot];            // ds_read_b128, broadcast
            lx = wc.x; ly = wc.y; lz = wc.z;
            a_last = (wslot == repslot) ? rep_a : kept_a;

            // ---- deferred flush (wave 3): vmcnt(0) covers the batch issued
            // 16 iterations ago (free); publish it; issue new batch, no drain.
            if (((k & 15) == 15) && wid == 3) {
                asm volatile("s_waitcnt vmcnt(0)" ::: "memory");
                if (lane == 0 && k >= 31)
                    __hip_atomic_store(&prog[blk], k - 15, __ATOMIC_RELAXED, __HIP_MEMORY_SCOPE_AGENT);
                if (lane < 16) {
                    int kk = k - 15 + lane;
                    float4 o = s_obuf[kk];
                    int sgO = soff + kk;
                    size_t base = (size_t)b * 3 * S_TOT;
                    st_wt_f32(&out0[base + sgO], o.x);
                    st_wt_f32(&out0[base + S_TOT + sgO], o.y);
                    st_wt_f32(&out0[base + 2 * S_TOT + sgO], o.z);
                    st_wt_f32(&out2[(size_t)b * S_TOT + sgO], o.w);
                }
            }
        }
        __syncthreads();   // full drain (implicit vmcnt 0); last batch done here
        if (wid == 3) {    // publish penultimate batch, store+publish final 16
            if (lane == 0)
                __hip_atomic_store(&prog[blk], K - 16, __ATOMIC_RELAXED, __HIP_MEMORY_SCOPE_AGENT);
            if (lane < 16) {
                int kk = K - 16 + lane;
                float4 o = s_obuf[kk];
                int sgO = soff + kk;
                size_t base = (size_t)b * 3 * S_TOT;
                st_wt_f32(&out0[base + sgO], o.x);
                st_wt_f32(&out0[base + S_TOT + sgO], o.y);
                st_wt_f32(&out0[base + 2 * S_TOT + sgO], o.z);
                st_wt_f32(&out2[(size_t)b * S_TOT + sgO], o.w);
            }
            asm volatile("s_waitcnt vmcnt(0)" ::: "memory");
            if (lane == 0) {
                __hip_atomic_store(&prog[blk], K, __ATOMIC_RELAXED, __HIP_MEMORY_SCOPE_AGENT);
                st_wt_u32((unsigned*)&fpsdone[blk], 1u);   // cleanup gate: FPS done
            }
        }
    } else if (blk < 16 + 1024) {
        // ---------------- points transpose (256 thr, 64x64 tile) ----------------
        float (*t)[65] = (float(*)[65])smem;
        int blk2 = blk - 16;
        int b = blk2 >> 7;
        int n0 = (blk2 & 127) * 64;
        int tx = tid & 63, ty = tid >> 6;      // ty in 0..3
        for (int c = ty; c < 64; c += 4)
            t[c][tx] = pts[((size_t)b * DFEAT + c) * NPTS + n0 + tx];
        __syncthreads();
        {
            unsigned* pTu = (unsigned*)ptsTh;
            int txc = tid & 31, rr = tid >> 5;   // 32 u32 cols x 8 row phases
            for (int r = rr; r < 64; r += 8) {
                unsigned lo = f2b(t[2 * txc][r]);
                unsigned hi = f2b(t[2 * txc + 1][r]);
                st_wt_u32(&pTu[((size_t)b * NPTS + n0 + r) * 32 + txc],
                          lo | (hi << 16));
            }
        }
        asm volatile("s_waitcnt vmcnt(0)" ::: "memory");   // per-wave drain
        __syncthreads();                                   // all waves drained
        if (tid == 0)
            __hip_atomic_fetch_add(tcount, 1, __ATOMIC_RELAXED, __HIP_MEMORY_SCOPE_AGENT);
    } else if (blk < 1076) {
        // ---------------- weight pack (all stores in wave 0) ----------------
        if (tid < 64) {
            int t = blk - (16 + 1024), l = tid;
            int kq = (l >> 4) * 8, n16 = l & 15;
            unsigned short o[8];
#pragma unroll
            for (int j = 0; j < 8; j++) {
                float v;
                if (t < 12) {
                    int kt = t >> 2, nt = t & 3;
                    int k = kt * 32 + kq + j, n = nt * 16 + n16;
                    v = (k < 64) ? w0[n * INCH + 3 + k] : (k < 67 ? w0[n * INCH + (k - 64)] : 0.0f);
                } else if (t < 20) {
                    int tt = t - 12, kt = tt >> 2, nt = tt & 3;
                    v = w1[(nt * 16 + n16) * 64 + kt * 32 + kq + j];
                } else {
                    int tt = t - 20, kt = tt >> 3, nt = tt & 7;
                    v = w2[(nt * 16 + n16) * 64 + kt * 32 + kq + j];
                }
                o[j] = f2b(v);
            }
            unsigned* wpu = (unsigned*)wp;
            size_t baseu = (size_t)t * 256 + l * 4;
#pragma unroll
            for (int j = 0; j < 4; j++)
                st_wt_u32(&wpu[baseu + j],
                          (unsigned)o[2 * j] | ((unsigned)o[2 * j + 1] << 16));
            asm volatile("s_waitcnt vmcnt(0)" ::: "memory");  // wave-0 drain
            if (tid == 0)
                __hip_atomic_fetch_add(tcount, 1, __ATOMIC_RELAXED, __HIP_MEMORY_SCOPE_AGENT);
        }
    } else {
        // ---------------- streamed ball+MLP consumers ----------------
        int lane = tid & 63, wid = tid >> 6;
        int w = (blk - 1076) * 4 + wid;        // production-ordered wave id
        int b, grp, kk;
        if (w < 2048) { kk = w >> 4; int r = w & 15; b = r & 7; grp = r >> 3; }
        else          { int w2 = w - 2048; kk = 128 + (w2 >> 3); b = w2 & 7; grp = 1; }
        int sg = (grp ? 128 : 0) + kk;
        int q = b * 512 + sg;
        int pblk = b * 2 + grp;

        // Bounded poll: 500 x s_sleep(64) ~ 2.0M cycles. Timeout/overflow ->
        // defer to cleanup.
        int ok = 1;
        for (int to = 0;;) {
            int p = __hip_atomic_load(&prog[pblk], __ATOMIC_RELAXED, __HIP_MEMORY_SCOPE_AGENT);
            if (p < 0) { ok = 0; break; }      // producer overflowed -> fallback path
            if (p > kk) {
                int t = __hip_atomic_load(tcount, __ATOMIC_RELAXED, __HIP_MEMORY_SCOPE_AGENT);
                if (t >= TDONE) break;         // point + transposed feats + weights ready
            }
            if (++to > 500) { ok = 0; break; }
            __builtin_amdgcn_s_sleep(64);
        }
        if (!ok) {
            if (lane == 0) skip[q] = 1;        // visible to cleanup at kernel boundary
            return;
        }
        __builtin_amdgcn_fence(__ATOMIC_ACQUIRE, "agent");  // buffer_inv: fresh reads

        short* sBufW = (short*)(smem + wid * BALLW);
        int* s_idxW = (int*)(smem + wid * BALLW + 13312);
        ball_one(xyz, ptsTh, wp, b0v, b1v, b2v, out0, out1, b, sg, lane, sBufW, s_idxW);
    }
}

// ---------------------------------------------------------------------------
// CLEANUP kernel (R20-verified): merges gated FPS fallback + ball tail.
//   blocks 0..15 : full-input FPS fallback, gated on (fpsdone==0 || M>CCAP).
//                  ALL 16 blocks increment fpsfb when done (gated or not).
//   blocks 16..79: ball for skipped q's. Fast path (no skips) exits without
//                  waiting. Slow path waits fpsfb==16 (all blocks co-resident
//                  -> guaranteed progress, bounded poll -> no hang).
// ---------------------------------------------------------------------------
__global__ __launch_bounds__(1024, 1) void cleanup(
    const float* __restrict__ xyz, const float* __restrict__ attn,
    const int* __restrict__ hdr,
    float* __restrict__ out0, float* __restrict__ out2,
    const unsigned short* __restrict__ ptsTh,
    const unsigned short* __restrict__ wp,
    const float* __restrict__ b0, const float* __restrict__ b1,
    const float* __restrict__ b2,
    float* __restrict__ out1,
    const int* __restrict__ skip,
    const int* __restrict__ fpsdone, int* __restrict__ fpsfb)
{
    __shared__ __align__(16) char smem[4 * BALLW];   // 54272 B union
    int blk = blockIdx.x;
    int tid = threadIdx.x;

    if (blk < 16) {
        // ---------------- gated FPS fallback (fps_kernel body) ----------------
        int need = (fpsdone[blk] == 0) || (hdr[blk * 2] > CCAP);
        if (!need) {
            if (tid == 0)
                __hip_atomic_fetch_add(fpsfb, 1, __ATOMIC_RELAXED, __HIP_MEMORY_SCOPE_AGENT);
            return;
        }
        unsigned long long* s_red = (unsigned long long*)smem;   // [2][16]
        int b = blk >> 1, grp = blk & 1;
        int K = grp ? 384 : 128;
        int soff = grp ? 128 : 0;
        int lane = tid & 63, wid = tid >> 6;
        const float* xb = xyz + (size_t)b * 3 * NPTS;
        const float* ab = attn + (size_t)b * NPTS;

        float px[8], py[8], pz[8], md[8];
#pragma unroll
        for (int i = 0; i < 8; i++) {
            int n = tid + i * 1024;
            float a = ab[n];
            float f = grp ? __fsub_rn(1.0f, a) : a;
            px[i] = __fmul_rn(f, xb[n]);
            py[i] = __fmul_rn(f, xb[NPTS + n]);
            pz[i] = __fmul_rn(f, xb[2 * NPTS + n]);
            md[i] = 1e10f;
        }
        float a_last = ab[0];
        float f0 = grp ? __fsub_rn(1.0f, a_last) : a_last;
        float lx = __fmul_rn(f0, xb[0]);
        float ly = __fmul_rn(f0, xb[NPTS]);
        float lz = __fmul_rn(f0, xb[2 * NPTS]);

        for (int k = 0; k < K; k++) {
            if (tid == 0) {
                int sg = soff + k;
                out0[(size_t)b * 3 * S_TOT + sg] = lx;
                out0[(size_t)b * 3 * S_TOT + S_TOT + sg] = ly;
                out0[(size_t)b * 3 * S_TOT + 2 * S_TOT + sg] = lz;
                out2[(size_t)b * S_TOT + sg] = a_last;
            }
            if (k == K - 1) break;
            float bv = -1.0f; int bi = 0;
#pragma unroll
            for (int i = 0; i < 8; i++) {
                float d2 = d2_exact(px[i], py[i], pz[i], lx, ly, lz);
                md[i] = fminf(md[i], d2);
                if (md[i] > bv) { bv = md[i]; bi = tid + i * 1024; }
            }
            unsigned long long best =
                ((unsigned long long)__float_as_uint(bv) << 32) | (unsigned)(~bi);
#pragma unroll
            for (int off = 32; off >= 1; off >>= 1) {
                unsigned long long o = __shfl_down(best, off);
                best = (o > best) ? o : best;
            }
            if (lane == 0) s_red[(k & 1) * 16 + wid] = best;
            __syncthreads();
            unsigned long long r = (lane < 16) ? s_red[(k & 1) * 16 + lane] : 0ull;
#pragma unroll
            for (int off = 8; off >= 1; off >>= 1) {
                unsigned long long o = __shfl_down(r, off);
                r = (o > r) ? o : r;
            }
            r = __shfl(r, 0);
            int n = (int)(~(unsigned)r);
            a_last = ab[n];
            float fl = grp ? __fsub_rn(1.0f, a_last) : a_last;
            lx = __fmul_rn(fl, xb[n]);
            ly = __fmul_rn(fl, xb[NPTS + n]);
            lz = __fmul_rn(fl, xb[2 * NPTS + n]);
        }
        __syncthreads();
        if (tid == 0) {
            __builtin_amdgcn_fence(__ATOMIC_RELEASE, "agent");   // pathological path only
            __hip_atomic_fetch_add(fpsfb, 1, __ATOMIC_RELAXED, __HIP_MEMORY_SCOPE_AGENT);
        }
    } else {
        // ---------------- ball for skipped q's ----------------
        if (tid >= 256) return;
        int lane = tid & 63, wid = tid >> 6;
        int q0 = ((blk - 16) * 4 + wid) * 16;
        int any = 0;
#pragma unroll 1
        for (int i = 0; i < 16; i++) any |= skip[q0 + i];
        if (!any) return;                                        // fast path
        for (int to = 0; to < 4000; ++to) {                      // wait FPS redo
            if (__hip_atomic_load(fpsfb, __ATOMIC_RELAXED, __HIP_MEMORY_SCOPE_AGENT) >= 16) break;
            __builtin_amdgcn_s_sleep(64);
        }
        __builtin_amdgcn_fence(__ATOMIC_ACQUIRE, "agent");
        short* sBufW = (short*)(smem + wid * BALLW);
        int* s_idxW = (int*)(smem + wid * BALLW + 13312);
#pragma unroll 1
        for (int i = 0; i < 16; i++) {
            int q = q0 + i;
            if (skip[q] == 0) continue;
            int b = q >> 9, sg = q & 511;
            ball_one(xyz, ptsTh, wp, b0, b1, b2, out0, out1, b, sg, lane, sBufW, s_idxW);
        }
    }
}

// ---------------------------------------------------------------------------
// Fallback FPS for the small-ws path (hdr==nullptr -> always runs).
// ---------------------------------------------------------------------------
__global__ __launch_bounds__(1024, 1) void fps_kernel(
    const float* __restrict__ xyz, const float* __restrict__ attn,
    const int* __restrict__ hdr,
    float* __restrict__ out0, float* __restrict__ out2)
{
    int blk = blockIdx.x;
    if (hdr != nullptr && hdr[blk * 2] <= CCAP) return;
    int b = blk >> 1, grp = blk & 1;
    int K = grp ? 384 : 128;
    int soff = grp ? 128 : 0;
    int tid = threadIdx.x, lane = tid & 63, wid = tid >> 6;
    const float* xb = xyz + (size_t)b * 3 * NPTS;
    const float* ab = attn + (size_t)b * NPTS;

    float px[8], py[8], pz[8], md[8];
#pragma unroll
    for (int i = 0; i < 8; i++) {
        int n = tid + i * 1024;
        float a = ab[n];
        float f = grp ? __fsub_rn(1.0f, a) : a;
        px[i] = __fmul_rn(f, xb[n]);
        py[i] = __fmul_rn(f, xb[NPTS + n]);
        pz[i] = __fmul_rn(f, xb[2 * NPTS + n]);
        md[i] = 1e10f;
    }
    __shared__ unsigned long long s_red[2][16];
    float a_last = ab[0];
    float f0 = grp ? __fsub_rn(1.0f, a_last) : a_last;
    float lx = __fmul_rn(f0, xb[0]);
    float ly = __fmul_rn(f0, xb[NPTS]);
    float lz = __fmul_rn(f0, xb[2 * NPTS]);

    for (int k = 0; k < K; k++) {
        if (tid == 0) {
            int sg = soff + k;
            out0[(size_t)b * 3 * S_TOT + sg] = lx;
            out0[(size_t)b * 3 * S_TOT + S_TOT + sg] = ly;
            out0[(size_t)b * 3 * S_TOT + 2 * S_TOT + sg] = lz;
            out2[(size_t)b * S_TOT + sg] = a_last;
        }
        if (k == K - 1) break;
        float bv = -1.0f; int bi = 0;
#pragma unroll
        for (int i = 0; i < 8; i++) {
            float d2 = d2_exact(px[i], py[i], pz[i], lx, ly, lz);
            md[i] = fminf(md[i], d2);
            if (md[i] > bv) { bv = md[i]; bi = tid + i * 1024; }
        }
        unsigned long long best =
            ((unsigned long long)__float_as_uint(bv) << 32) | (unsigned)(~bi);
#pragma unroll
        for (int off = 32; off >= 1; off >>= 1) {
            unsigned long long o = __shfl_down(best, off);
            best = (o > best) ? o : best;
        }
        if (lane == 0) s_red[k & 1][wid] = best;
        __syncthreads();
        unsigned long long r = (lane < 16) ? s_red[k & 1][lane] : 0ull;
#pragma unroll
        for (int off = 8; off >= 1; off >>= 1) {
            unsigned long long o = __shfl_down(r, off);
            r = (o > r) ? o : r;
        }
        r = __shfl(r, 0);
        int n = (int)(~(unsigned)r);
        a_last = ab[n];
        float fl = grp ? __fsub_rn(1.0f, a_last) : a_last;
        lx = __fmul_rn(fl, xb[n]);
        ly = __fmul_rn(fl, xb[NPTS + n]);
        lz = __fmul_rn(fl, xb[2 * NPTS + n]);
    }
}

// ---------------------------------------------------------------------------
// Fallback ball+MLP (no ws): unchanged from R6.
// ---------------------------------------------------------------------------
__global__ __launch_bounds__(64, 1) void ball_mlp_fb(
    const float* __restrict__ xyz, const float* __restrict__ pts,
    const float* __restrict__ w0, const float* __restrict__ b0,
    const float* __restrict__ w1, const float* __restrict__ b1,
    const float* __restrict__ w2, const float* __restrict__ b2,
    const float* __restrict__ out0, float* __restrict__ out1)
{
    const float R2 = (float)(0.4 * 0.4);
    int q = blockIdx.x;
    int b = q >> 9, sg = q & 511, lane = threadIdx.x;
    const float* xb = xyz + (size_t)b * 3 * NPTS;
    float qx = out0[(size_t)b * 3 * S_TOT + sg];
    float qy = out0[(size_t)b * 3 * S_TOT + S_TOT + sg];
    float qz = out0[(size_t)b * 3 * S_TOT + 2 * S_TOT + sg];

    __shared__ int s_idx[NSAMP];
    __shared__ float s_h[32 * 64];
    int cnt = 0;
    for (int base = 0; base < NPTS; base += 64) {
        int n = base + lane;
        float d2 = d2_exact(qx, qy, qz, xb[n], xb[NPTS + n], xb[2 * NPTS + n]);
        bool flag = d2 < R2;
        unsigned long long m = __ballot(flag);
        int pos = cnt + (int)__popcll(m & ((1ull << lane) - 1ull));
        if (flag && pos < NSAMP) s_idx[pos] = n;
        cnt += (int)__popcll(m);
    }
    if (cnt > NSAMP) cnt = NSAMP;
    int nb = (lane < cnt) ? s_idx[lane] : -1;
    float nx_ = 0.f, ny_ = 0.f, nz_ = 0.f;
    if (nb >= 0) { nx_ = xb[nb]; ny_ = xb[NPTS + nb]; nz_ = xb[2 * NPTS + nb]; }
    float fx = nx_ - qx, fy = ny_ - qy, fz = nz_ - qz;
    int row = (nb < 0) ? (NPTS - 1) : nb;

    float h1[64];
#pragma unroll
    for (int o = 0; o < 64; o++) {
        float a = __builtin_fmaf(w0[o * INCH + 0], fx, b0[o]);
        a = __builtin_fmaf(w0[o * INCH + 1], fy, a);
        h1[o] = __builtin_fmaf(w0[o * INCH + 2], fz, a);
    }
    const float* pb = pts + (size_t)b * DFEAT * NPTS + row;
#pragma unroll 1
    for (int c = 0; c < 64; c++) {
        float f = pb[(size_t)c * NPTS];
#pragma unroll
        for (int o = 0; o < 64; o++)
            h1[o] = __builtin_fmaf(w0[o * INCH + 3 + c], f, h1[o]);
    }
#pragma unroll
    for (int c = 0; c < 32; c++) s_h[c * 64 + lane] = fmaxf(h1[c], 0.0f);
    float h1h[32];
#pragma unroll
    for (int c = 0; c < 32; c++) h1h[c] = fmaxf(h1[32 + c], 0.0f);

    float h2[64];
#pragma unroll
    for (int o = 0; o < 64; o++) h2[o] = b1[o];
#pragma unroll 1
    for (int c = 0; c < 32; c++) {
        float hc = s_h[c * 64 + lane];
#pragma unroll
        for (int o = 0; o < 64; o++)
            h2[o] = __builtin_fmaf(w1[o * 64 + c], hc, h2[o]);
    }
#pragma unroll
    for (int c = 0; c < 32; c++) s_h[c * 64 + lane] = h1h[c];
#pragma unroll 1
    for (int c = 0; c < 32; c++) {
        float hc = s_h[c * 64 + lane];
#pragma unroll
        for (int o = 0; o < 64; o++)
            h2[o] = __builtin_fmaf(w1[o * 64 + (32 + c)], hc, h2[o]);
    }
#pragma unroll
    for (int o = 0; o < 64; o++) h2[o] = fmaxf(h2[o], 0.0f);

#pragma unroll 2
    for (int o = 0; o < 128; o++) {
        const float* wr = w2 + o * 64;
        float acc = b2[o];
#pragma unroll
        for (int c = 0; c < 64; c++) acc = __builtin_fmaf(wr[c], h2[c], acc);
        acc = fmaxf(acc, 0.0f);
#pragma unroll
        for (int off = 32; off >= 1; off >>= 1)
            acc = fmaxf(acc, __shfl_down(acc, off));
        if (lane == 0) out1[((size_t)(b * 128 + o)) * S_TOT + sg] = acc;
    }
}

extern "C" void kernel_launch(void* const* d_in, const int* in_sizes, int n_in,
                              void* d_out, int out_size, void* d_ws, size_t ws_size,
                              hipStream_t stream) {
    const float* xyz  = (const float*)d_in[0];
    const float* pts  = (const float*)d_in[1];
    const float* attn = (const float*)d_in[2];
    const float* w0 = (const float*)d_in[3];
    const float* b0 = (const float*)d_in[4];
    const float* w1 = (const float*)d_in[5];
    const float* b1 = (const float*)d_in[6];
    const float* w2 = (const float*)d_in[7];
    const float* b2 = (const float*)d_in[8];

    float* out0 = (float*)d_out;                    // [B,3,S]
    float* out1 = out0 + (size_t)NB * 3 * S_TOT;    // [B,128,S]
    float* out2 = out1 + (size_t)NB * 128 * S_TOT;  // [B,1,S]

    // ws: wp | ptsTh | cxyz | hdr | prog/tcnt/skip/fpsdn/fpsfb
    unsigned short* wp    = (unsigned short*)d_ws;
    unsigned short* ptsTh = (unsigned short*)((char*)d_ws + 36864);
    float4*         cxyz  = (float4*)((char*)d_ws + 36864 + 8388608);
    int*            hdr   = (int*)((char*)cxyz + (size_t)16 * CCAP * 16);
    int*            prog  = hdr + 32;        // 16 ints
    int*            tcnt  = prog + 16;       // 4 ints
    int*            skip  = tcnt + 4;        // 4096 ints
    int*            fpsdn = skip + 4096;     // 16 ints
    int*            fpsfb = fpsdn + 16;      // 16 ints (1 used)
    const size_t ctrl_bytes = (size_t)(16 + 4 + 4096 + 16 + 16) * 4;
    const size_t need = 36864 + 8388608 + (size_t)16 * CCAP * 16 + 128
                        + ctrl_bytes + 64;

    if (ws_size >= need) {
        fps_compact<<<16, 1024, 0, stream>>>(xyz, attn, cxyz, hdr,
                                             prog, tcnt, skip, fpsdn, fpsfb);
        fps_fused<<<16 + 1024 + 36 + 1024, 256, 0, stream>>>(
            attn, cxyz, hdr, out0, out2, pts, ptsTh, w0, w1, w2, wp,
            xyz, b0, b1, b2, out1, prog, tcnt, skip, fpsdn);
        cleanup<<<80, 1024, 0, stream>>>(xyz, attn, hdr, out0, out2, ptsTh, wp,
                                         b0, b1, b2, out1, skip, fpsdn, fpsfb);
    } else {
        fps_kernel<<<16, 1024, 0, stream>>>(xyz, attn, nullptr, out0, out2);
        ball_mlp_fb<<<NB * S_TOT, 64, 0, stream>>>(xyz, pts, w0, b0, w1, b1,
                                                   w2, b2, out0, out1);
    }
}